// Round 12
// baseline (270.046 us; speedup 1.0000x reference)
//
#include <hip/hip_runtime.h>
#include <cstdint>
#include <cstddef>

typedef int int32x4  __attribute__((ext_vector_type(4)));
typedef int int32x16 __attribute__((ext_vector_type(16)));

#define AS1 __attribute__((address_space(1)))
#define AS3 __attribute__((address_space(3)))

__device__ __forceinline__ void gload_lds16(const void* g, void* l) {
    __builtin_amdgcn_global_load_lds((const AS1 void*)g, (AS3 void*)l, 16, 0, 0);
}

#define MFMA_I8(a, b, c) __builtin_amdgcn_mfma_i32_32x32x32_i8((a), (b), (c), 0, 0, 0)

// ---------------------------------------------------------------------------
// Fused quant kernel (frozen r6 version).
// Blocks [0,4096): x-rows. Blocks [4096,5120): y 256n x 64k coalesced tiles.
// ---------------------------------------------------------------------------
__global__ __launch_bounds__(256) void quant_xy(const float* __restrict__ x,
                                                const float* __restrict__ y,
                                                signed char* __restrict__ A8,
                                                signed char* __restrict__ B8T,
                                                int* __restrict__ rs,
                                                int* __restrict__ sy) {
    const int t = threadIdx.x;
    if (blockIdx.x < 4096) {
        const int row = blockIdx.x;
        const float4* xr = (const float4*)(x + (size_t)row * 4096);
        char4* ar = (char4*)(A8 + (size_t)row * 4096);
        int s = 0;
#pragma unroll
        for (int i = 0; i < 4; i++) {
            const int idx = i * 256 + t;
            float4 v = xr[idx];
            int a0 = (int)v.x, a1 = (int)v.y, a2 = (int)v.z, a3 = (int)v.w;
            s += a0 + a1 + a2 + a3;
            char4 c;
            c.x = (signed char)a0; c.y = (signed char)a1;
            c.z = (signed char)a2; c.w = (signed char)a3;
            ar[idx] = c;
        }
#pragma unroll
        for (int off = 32; off > 0; off >>= 1) s += __shfl_down(s, off);
        __shared__ int wsum[4];
        if ((t & 63) == 0) wsum[t >> 6] = s;
        __syncthreads();
        if (t == 0) rs[row] = wsum[0] + wsum[1] + wsum[2] + wsum[3];
    } else {
        const int q = blockIdx.x - 4096;
        const int nt = (q & 15) * 256;
        const int kt = (q >> 4) * 64;
        __shared__ int tile_s[256 * 16];
        __shared__ int ssum[256];
        if (t < 256) ssum[t] = 0;
        __syncthreads();

        const int n4 = (t & 63) * 4;
        const int kg = (t >> 6) * 4;
        const int swzkey = t & 15;
        int s0 = 0, s1 = 0, s2 = 0, s3 = 0;
#pragma unroll
        for (int o = 0; o < 4; o++) {
            int b[4][4];
#pragma unroll
            for (int i = 0; i < 4; i++) {
                const int k = o * 16 + kg + i;
                float4 v = *(const float4*)(y + (size_t)(kt + k) * 4096 + nt + n4);
                b[i][0] = (int)v.x - 128; b[i][1] = (int)v.y - 128;
                b[i][2] = (int)v.z - 128; b[i][3] = (int)v.w - 128;
            }
            const int kd = o * 4 + (t >> 6);
            const int sw = kd ^ swzkey;
#pragma unroll
            for (int j = 0; j < 4; j++) {
                const int w = (b[0][j] & 255) | ((b[1][j] & 255) << 8) |
                              ((b[2][j] & 255) << 16) | (b[3][j] << 24);
                tile_s[(n4 + j) * 16 + sw] = w;
            }
            s0 += b[0][0] + b[1][0] + b[2][0] + b[3][0];
            s1 += b[0][1] + b[1][1] + b[2][1] + b[3][1];
            s2 += b[0][2] + b[1][2] + b[2][2] + b[3][2];
            s3 += b[0][3] + b[1][3] + b[2][3] + b[3][3];
        }
        atomicAdd(&ssum[n4 + 0], s0);
        atomicAdd(&ssum[n4 + 1], s1);
        atomicAdd(&ssum[n4 + 2], s2);
        atomicAdd(&ssum[n4 + 3], s3);
        __syncthreads();

        const int c = t & 3;
#pragma unroll
        for (int p = 0; p < 4; p++) {
            const int n = (t >> 2) + p * 64;
            const int key = (n >> 2) & 15;
            int32x4 o;
            o.x = tile_s[n * 16 + ((c * 4 + 0) ^ key)];
            o.y = tile_s[n * 16 + ((c * 4 + 1) ^ key)];
            o.z = tile_s[n * 16 + ((c * 4 + 2) ^ key)];
            o.w = tile_s[n * 16 + ((c * 4 + 3) ^ key)];
            *(int32x4*)(B8T + (size_t)(nt + n) * 4096 + kt + c * 16) = o;
        }
        if (t < 256) atomicAdd(&sy[nt + t], ssum[t]);
    }
}

// ---------------------------------------------------------------------------
// Kernel 3: int8 GEMM — MAX REGISTER TILE round (0.5 LDS reads per MFMA).
// Ledger: schedules null (r0/r1/r3); small-tile ✗ (r2); reg-pipeline +12%
// (r4); A-from-global ✗ (r7); block-TLP null (r9); BK=128 win (r10, 74.7us);
// 4 waves/SIMD null (r11: Occupancy 2x -> dur unchanged) => limiter is a
// SHARED per-CU resource. Pipe accounting: LDS is the most-loaded pipe
// (~72% in r11: 256 b128 frag reads + 1024 conflict cyc + writes per tile)
// — frag reads are duplicated across waves sharing a wave-row (1.5-2.0
// reads/MFMA). Fix: maximal wave tile 128x128 (acc[4][4] = 256 regs, legal
// at 1 wave/SIMD under the 512-VGPR budget): 8 reads feed 16 MFMAs = 0.5
// reads/MFMA; LDS/CU/tile drops to ~128 reads (~2100 cyc) < MFMA demand
// (2343 cyc/SIMD) for the first time. Quarter = 16 INDEPENDENT MFMAs
// (586 cyc) covering the next quarter's 8 reads.
// Geometry: 256 blocks x 256 thr (4 waves 2Mx2N), block tile 256x256,
// BK=128, 2-ring LDS 128KB (r10 layout verbatim). K-loop skeleton = r10:
// 4 quarters (s in {0,1} x ks in {0,1}), X/Y register frag alternation,
// stage(t+1) split A->q0 B->q1 (16 gloads/thread/tile, p=0..3), ONE
// vmcnt(0)+lgkmcnt(0)+barrier boundary per tile, q3 prefetches tile t+1.
// Staging (m104/m108 discipline): dst = ring + s*16384 + p*4096 + tid*16;
// source row p*64+(tid>>2), chunk (tid&3)^((tid>>3)&3) (p*64 contributes 0
// mod 4 to (row>>1)&3 — same derivation as r4/r9/r10).
// Pre-committed failure reads: VGPR>400 / dur>=100 => spill; dur 74-90 &
// MfmaUtil ~40 => shared-resource cap is MFMA-effective-rate itself =>
// declare ceiling.
// Frags: A[m=lane&31][k=(lane>>5)*16+j]; C/D col=lane&31,
// row=(reg&3)+8*(reg>>2)+4*(lane>>5)  (verified r0-r11, absmax 32).
// Epilogue: C = 7.5e-4 * (P - 32*rs[m] + 66*sy[n] - 8650752)
// ---------------------------------------------------------------------------
__global__ __launch_bounds__(256, 1) void gemm_i8(const signed char* __restrict__ A8,
                                                  const signed char* __restrict__ B8T,
                                                  const int* __restrict__ rs,
                                                  const int* __restrict__ sy,
                                                  float* __restrict__ C) {
    __shared__ __align__(16) signed char As[2 * 32768];  // ring x (2 sub x 16KB)
    __shared__ __align__(16) signed char Bs[2 * 32768];
    const int tid = threadIdx.x;
    const int lin = blockIdx.x;
    const int til = (lin & 7) * 32 + (lin >> 3);   // XCD-contiguous tiles
    const int bm = (til >> 4) * 256;
    const int bn = (til & 15) * 256;
    const int lane = tid & 63;
    const int wave = tid >> 6;          // 0..3
    const int wm = (wave >> 1) * 128;   // 2 m-waves x 128
    const int wn = (wave & 1) * 128;    // 2 n-waves x 128
    const int mr = lane & 31;
    const int kh = lane >> 5;

    int32x16 acc[4][4] = {};

    // staging: thread -> row p*64+(tid>>2), source chunk (tid&3)^((tid>>3)&3);
    // dst = uniform base + tid*16 (+p*4096): matches global_load_lds layout.
    const size_t srowoff = (size_t)(tid >> 2) * 4096 +
                           (((tid & 3) ^ ((tid >> 3) & 3)) * 16);
    const size_t arow = (size_t)bm * 4096 + srowoff;
    const size_t brow = (size_t)bn * 4096 + srowoff;

    // fragment LDS offsets within a 16KB subtile: row*64 + slot*16,
    // slot = (ks*2+kh) ^ ((mr>>1)&3)
    int aoff[4][2], boff[4][2];
#pragma unroll
    for (int ks = 0; ks < 2; ks++) {
        const int slot = ((ks * 2 + kh) ^ ((mr >> 1) & 3)) * 16;
#pragma unroll
        for (int i = 0; i < 4; i++) aoff[i][ks] = (wm + i * 32 + mr) * 64 + slot;
#pragma unroll
        for (int j = 0; j < 4; j++) boff[j][ks] = (wn + j * 32 + mr) * 64 + slot;
    }

    auto stageA = [&](int r, int kt) {   // 8 gloads: 2 sub x 4 p
#pragma unroll
        for (int s = 0; s < 2; s++)
#pragma unroll
            for (int p = 0; p < 4; p++)
                gload_lds16(A8 + arow + (size_t)p * 262144 + kt + s * 64,
                            As + r * 32768 + s * 16384 + p * 4096 + tid * 16);
    };
    auto stageB = [&](int r, int kt) {   // 8 gloads: 2 sub x 4 p
#pragma unroll
        for (int s = 0; s < 2; s++)
#pragma unroll
            for (int p = 0; p < 4; p++)
                gload_lds16(B8T + brow + (size_t)p * 262144 + kt + s * 64,
                            Bs + r * 32768 + s * 16384 + p * 4096 + tid * 16);
    };

#define QUARTER_MFMA(A_, B_)                                   \
    __builtin_amdgcn_s_setprio(1);                             \
    _Pragma("unroll")                                          \
    for (int i = 0; i < 4; i++)                                \
        _Pragma("unroll")                                      \
        for (int j = 0; j < 4; j++)                            \
            acc[i][j] = MFMA_I8(A_[i], B_[j], acc[i][j]);      \
    __builtin_amdgcn_s_setprio(0);

    // waitcnt imm: vmcnt[3:0]=bits0-3, vmcnt[5:4]=bits14-15, lgkm=bits8-11.
    // 0xF70 = vmcnt(0) lgkm-ignore. 0x070 = vmcnt(0)+lgkmcnt(0).
    stageA(0, 0);
    stageB(0, 0);
    __builtin_amdgcn_s_waitcnt(0xF70);
    __builtin_amdgcn_s_barrier();
    __builtin_amdgcn_sched_barrier(0);

    int32x4 xa[4], xb[4];   // frags for even quarters (q0, q2)
    int32x4 ya[4], yb[4];   // frags for odd quarters (q1, q3)
#pragma unroll
    for (int i = 0; i < 4; i++) xa[i] = *(const int32x4*)(As + aoff[i][0]);
#pragma unroll
    for (int j = 0; j < 4; j++) xb[j] = *(const int32x4*)(Bs + boff[j][0]);

#pragma unroll 1
    for (int t = 0; t < 32; ++t) {
        const signed char* Ac = As + (t & 1) * 32768;        // ring: tile t
        const signed char* Bc = Bs + (t & 1) * 32768;
        const signed char* An = As + ((t + 1) & 1) * 32768;  // ring: tile t+1
        const signed char* Bn = Bs + ((t + 1) & 1) * 32768;

        // ---- q0: read Y <- (t, s0, ks1); issue stageA(t+1); MFMA X ----
#pragma unroll
        for (int i = 0; i < 4; i++) ya[i] = *(const int32x4*)(Ac + aoff[i][1]);
#pragma unroll
        for (int j = 0; j < 4; j++) yb[j] = *(const int32x4*)(Bc + boff[j][1]);
        if (t < 31) stageA((t + 1) & 1, (t + 1) * 128);
        __builtin_amdgcn_sched_barrier(0);
        QUARTER_MFMA(xa, xb)
        __builtin_amdgcn_sched_barrier(0);

        // ---- q1: read X <- (t, s1, ks0); issue stageB(t+1); MFMA Y ----
#pragma unroll
        for (int i = 0; i < 4; i++) xa[i] = *(const int32x4*)(Ac + 16384 + aoff[i][0]);
#pragma unroll
        for (int j = 0; j < 4; j++) xb[j] = *(const int32x4*)(Bc + 16384 + boff[j][0]);
        if (t < 31) stageB((t + 1) & 1, (t + 1) * 128);
        __builtin_amdgcn_sched_barrier(0);
        QUARTER_MFMA(ya, yb)
        __builtin_amdgcn_sched_barrier(0);

        // ---- q2: read Y <- (t, s1, ks1); MFMA X ----
#pragma unroll
        for (int i = 0; i < 4; i++) ya[i] = *(const int32x4*)(Ac + 16384 + aoff[i][1]);
#pragma unroll
        for (int j = 0; j < 4; j++) yb[j] = *(const int32x4*)(Bc + 16384 + boff[j][1]);
        __builtin_amdgcn_sched_barrier(0);
        QUARTER_MFMA(xa, xb)
        __builtin_amdgcn_sched_barrier(0);

        // ---- boundary: tile t+1 landed (own) + all reads of ring (t+1)&1
        //      drained (lgkm 0) -> barrier publishes both cross-wave ----
        __builtin_amdgcn_s_waitcnt(0x070);   // vmcnt(0) + lgkmcnt(0)
        __builtin_amdgcn_s_barrier();
        __builtin_amdgcn_sched_barrier(0);

        // ---- q3: read X <- (t+1, s0, ks0); MFMA Y ----
        if (t < 31) {
#pragma unroll
            for (int i = 0; i < 4; i++) xa[i] = *(const int32x4*)(An + aoff[i][0]);
#pragma unroll
            for (int j = 0; j < 4; j++) xb[j] = *(const int32x4*)(Bn + boff[j][0]);
        }
        __builtin_amdgcn_sched_barrier(0);
        QUARTER_MFMA(ya, yb)
    }
#undef QUARTER_MFMA

    // Epilogue. C/D: col = lane&31, row = (reg&3) + 8*(reg>>2) + 4*kh
#pragma unroll
    for (int i = 0; i < 4; i++) {
#pragma unroll
        for (int r = 0; r < 16; r++) {
            const int gm = bm + wm + i * 32 + (r & 3) + 8 * (r >> 2) + 4 * kh;
            const int rcorr = -32 * rs[gm] - 8650752;
#pragma unroll
            for (int j = 0; j < 4; j++) {
                const int gn = bn + wn + j * 32 + mr;
                const int v = acc[i][j][r] + rcorr + 66 * sy[gn];
                C[(size_t)gm * 4096 + gn] = 7.5e-4f * (float)v;
            }
        }
    }
}

// ---------------------------------------------------------------------------
extern "C" void kernel_launch(void* const* d_in, const int* in_sizes, int n_in,
                              void* d_out, int out_size, void* d_ws, size_t ws_size,
                              hipStream_t stream) {
    const float* x = (const float*)d_in[0];  // [4096,4096] int8-valued
    const float* y = (const float*)d_in[1];  // [4096,4096] uint8-valued
    float* out = (float*)d_out;

    char* ws = (char*)d_ws;
    signed char* A8  = (signed char*)ws;                         // 16 MiB
    signed char* B8T = (signed char*)(ws + (16u << 20));         // 16 MiB
    int* rs = (int*)(ws + (32u << 20));                          // 16 KiB
    int* sy = (int*)(ws + (32u << 20) + (16u << 10));            // 16 KiB

    hipMemsetAsync(sy, 0, 4096 * sizeof(int), stream);
    quant_xy<<<5120, 256, 0, stream>>>(x, y, A8, B8T, rs, sy);
    gemm_i8<<<256, 256, 0, stream>>>(A8, B8T, rs, sy, out);
}

// Round 13
// 245.821 us; speedup vs baseline: 1.0986x; 1.0986x over previous
//
#include <hip/hip_runtime.h>
#include <cstdint>
#include <cstddef>

typedef int int32x4  __attribute__((ext_vector_type(4)));
typedef int int32x16 __attribute__((ext_vector_type(16)));

#define AS1 __attribute__((address_space(1)))
#define AS3 __attribute__((address_space(3)))

__device__ __forceinline__ void gload_lds16(const void* g, void* l) {
    __builtin_amdgcn_global_load_lds((const AS1 void*)g, (AS3 void*)l, 16, 0, 0);
}

#define MFMA_I8(a, b, c) __builtin_amdgcn_mfma_i32_32x32x32_i8((a), (b), (c), 0, 0, 0)

// ---------------------------------------------------------------------------
// Fused quant kernel (frozen r6 version).
// Blocks [0,4096): x-rows. Blocks [4096,5120): y 256n x 64k coalesced tiles.
// ---------------------------------------------------------------------------
__global__ __launch_bounds__(256) void quant_xy(const float* __restrict__ x,
                                                const float* __restrict__ y,
                                                signed char* __restrict__ A8,
                                                signed char* __restrict__ B8T,
                                                int* __restrict__ rs,
                                                int* __restrict__ sy) {
    const int t = threadIdx.x;
    if (blockIdx.x < 4096) {
        const int row = blockIdx.x;
        const float4* xr = (const float4*)(x + (size_t)row * 4096);
        char4* ar = (char4*)(A8 + (size_t)row * 4096);
        int s = 0;
#pragma unroll
        for (int i = 0; i < 4; i++) {
            const int idx = i * 256 + t;
            float4 v = xr[idx];
            int a0 = (int)v.x, a1 = (int)v.y, a2 = (int)v.z, a3 = (int)v.w;
            s += a0 + a1 + a2 + a3;
            char4 c;
            c.x = (signed char)a0; c.y = (signed char)a1;
            c.z = (signed char)a2; c.w = (signed char)a3;
            ar[idx] = c;
        }
#pragma unroll
        for (int off = 32; off > 0; off >>= 1) s += __shfl_down(s, off);
        __shared__ int wsum[4];
        if ((t & 63) == 0) wsum[t >> 6] = s;
        __syncthreads();
        if (t == 0) rs[row] = wsum[0] + wsum[1] + wsum[2] + wsum[3];
    } else {
        const int q = blockIdx.x - 4096;
        const int nt = (q & 15) * 256;
        const int kt = (q >> 4) * 64;
        __shared__ int tile_s[256 * 16];
        __shared__ int ssum[256];
        if (t < 256) ssum[t] = 0;
        __syncthreads();

        const int n4 = (t & 63) * 4;
        const int kg = (t >> 6) * 4;
        const int swzkey = t & 15;
        int s0 = 0, s1 = 0, s2 = 0, s3 = 0;
#pragma unroll
        for (int o = 0; o < 4; o++) {
            int b[4][4];
#pragma unroll
            for (int i = 0; i < 4; i++) {
                const int k = o * 16 + kg + i;
                float4 v = *(const float4*)(y + (size_t)(kt + k) * 4096 + nt + n4);
                b[i][0] = (int)v.x - 128; b[i][1] = (int)v.y - 128;
                b[i][2] = (int)v.z - 128; b[i][3] = (int)v.w - 128;
            }
            const int kd = o * 4 + (t >> 6);
            const int sw = kd ^ swzkey;
#pragma unroll
            for (int j = 0; j < 4; j++) {
                const int w = (b[0][j] & 255) | ((b[1][j] & 255) << 8) |
                              ((b[2][j] & 255) << 16) | (b[3][j] << 24);
                tile_s[(n4 + j) * 16 + sw] = w;
            }
            s0 += b[0][0] + b[1][0] + b[2][0] + b[3][0];
            s1 += b[0][1] + b[1][1] + b[2][1] + b[3][1];
            s2 += b[0][2] + b[1][2] + b[2][2] + b[3][2];
            s3 += b[0][3] + b[1][3] + b[2][3] + b[3][3];
        }
        atomicAdd(&ssum[n4 + 0], s0);
        atomicAdd(&ssum[n4 + 1], s1);
        atomicAdd(&ssum[n4 + 2], s2);
        atomicAdd(&ssum[n4 + 3], s3);
        __syncthreads();

        const int c = t & 3;
#pragma unroll
        for (int p = 0; p < 4; p++) {
            const int n = (t >> 2) + p * 64;
            const int key = (n >> 2) & 15;
            int32x4 o;
            o.x = tile_s[n * 16 + ((c * 4 + 0) ^ key)];
            o.y = tile_s[n * 16 + ((c * 4 + 1) ^ key)];
            o.z = tile_s[n * 16 + ((c * 4 + 2) ^ key)];
            o.w = tile_s[n * 16 + ((c * 4 + 3) ^ key)];
            *(int32x4*)(B8T + (size_t)(nt + n) * 4096 + kt + c * 16) = o;
        }
        if (t < 256) atomicAdd(&sy[nt + t], ssum[t]);
    }
}

// ---------------------------------------------------------------------------
// Kernel 3: int8 GEMM — 128x128 wave tile, SINGLE-BUFFERED frags (fix r12
// spill). r12 evidence: conflicts 6.29M->4.19M tracked the 192->128KB/tile
// read cut (mechanism works), absmax 32 (staging/indexing correct), but
// VGPR=256 + WRITE_SIZE 237MB = spill (64 frag VGPRs + 32 unrolled gload
// addrs + 256 AGPR acc blew arch-VGPR). Fix: drop the X/Y frag double
// buffer -> af[4]/bf[4] only (32 VGPR). With 16 INDEPENDENT MFMAs per
// quarter (586cy pipe occupancy), single-buffer self-pipelines: WAR forces
// q+1's ds_reads to issue after q's MFMAs issue (~100cy in), landing ~150cy
// later — inside the window. Same hazard pattern r4/r10 proved safe. Only
// q0-of-tile has an exposed ~150cy lgkm stall.
// Geometry: 256 blocks x 256 thr (4 waves 2Mx2N), wave tile 128x128
// (acc[4][4] = 256 AGPR), block tile 256x256, BK=128, 2-ring LDS 128KB.
// Per tile: 4 quarters (s,ks) of {ds_read 8 frags, MFMA 16}; stage A(t+1)
// in q0, B(t+1) in q1 (16 gloads, r12 formulas verbatim); ONE
// vmcnt(0)+barrier boundary per tile (staging issued ~1800cy before wait).
// 2-ring safety: reads of ring t&1 all complete before their MFMAs issue,
// hence before the boundary barrier; stage(t+2) (next tile q0) writes ring
// t&1 only after that barrier.
// Staging (m104/m108): dst = ring + s*16384 + p*4096 + tid*16; source row
// p*64+(tid>>2), chunk (tid&3)^((tid>>3)&3).
// Pre-committed failure reads: VGPR=256/WRITE>100MB => spill persists,
// revert r10 + declare ceiling; dur 70-80 & MfmaUtil ~45 => 1-wave issue
// serialization, same conclusion.
// Frags: A[m=lane&31][k=(lane>>5)*16+j]; C/D col=lane&31,
// row=(reg&3)+8*(reg>>2)+4*(lane>>5)  (verified r0-r12, absmax 32).
// Epilogue: C = 7.5e-4 * (P - 32*rs[m] + 66*sy[n] - 8650752)
// ---------------------------------------------------------------------------
__global__ __launch_bounds__(256, 1) void gemm_i8(const signed char* __restrict__ A8,
                                                  const signed char* __restrict__ B8T,
                                                  const int* __restrict__ rs,
                                                  const int* __restrict__ sy,
                                                  float* __restrict__ C) {
    __shared__ __align__(16) signed char As[2 * 32768];  // ring x (2 sub x 16KB)
    __shared__ __align__(16) signed char Bs[2 * 32768];
    const int tid = threadIdx.x;
    const int lin = blockIdx.x;
    const int til = (lin & 7) * 32 + (lin >> 3);   // XCD-contiguous tiles
    const int bm = (til >> 4) * 256;
    const int bn = (til & 15) * 256;
    const int lane = tid & 63;
    const int wave = tid >> 6;          // 0..3
    const int wm = (wave >> 1) * 128;   // 2 m-waves x 128
    const int wn = (wave & 1) * 128;    // 2 n-waves x 128
    const int mr = lane & 31;
    const int kh = lane >> 5;

    int32x16 acc[4][4] = {};

    // staging: thread -> row p*64+(tid>>2), source chunk (tid&3)^((tid>>3)&3);
    // dst = uniform base + tid*16 (+p*4096): matches global_load_lds layout.
    const size_t srowoff = (size_t)(tid >> 2) * 4096 +
                           (((tid & 3) ^ ((tid >> 3) & 3)) * 16);
    const size_t arow = (size_t)bm * 4096 + srowoff;
    const size_t brow = (size_t)bn * 4096 + srowoff;

    // fragment LDS offsets within a 16KB subtile: row*64 + slot*16,
    // slot = (ks*2+kh) ^ ((mr>>1)&3)
    int aoff[4][2], boff[4][2];
#pragma unroll
    for (int ks = 0; ks < 2; ks++) {
        const int slot = ((ks * 2 + kh) ^ ((mr >> 1) & 3)) * 16;
#pragma unroll
        for (int i = 0; i < 4; i++) aoff[i][ks] = (wm + i * 32 + mr) * 64 + slot;
#pragma unroll
        for (int j = 0; j < 4; j++) boff[j][ks] = (wn + j * 32 + mr) * 64 + slot;
    }

    auto stageA = [&](int r, int kt) {   // 8 gloads: 2 sub x 4 p
#pragma unroll
        for (int s = 0; s < 2; s++)
#pragma unroll
            for (int p = 0; p < 4; p++)
                gload_lds16(A8 + arow + (size_t)p * 262144 + kt + s * 64,
                            As + r * 32768 + s * 16384 + p * 4096 + tid * 16);
    };
    auto stageB = [&](int r, int kt) {   // 8 gloads: 2 sub x 4 p
#pragma unroll
        for (int s = 0; s < 2; s++)
#pragma unroll
            for (int p = 0; p < 4; p++)
                gload_lds16(B8T + brow + (size_t)p * 262144 + kt + s * 64,
                            Bs + r * 32768 + s * 16384 + p * 4096 + tid * 16);
    };

    int32x4 af[4], bf[4];   // single-buffered fragment registers

#define READ_FRAGS(Abase, Bbase, sub, ks)                                    \
    _Pragma("unroll")                                                        \
    for (int i = 0; i < 4; i++)                                              \
        af[i] = *(const int32x4*)((Abase) + (sub) + aoff[i][ks]);            \
    _Pragma("unroll")                                                        \
    for (int j = 0; j < 4; j++)                                              \
        bf[j] = *(const int32x4*)((Bbase) + (sub) + boff[j][ks]);

#define QUARTER_MFMA                                                         \
    __builtin_amdgcn_s_setprio(1);                                           \
    _Pragma("unroll")                                                        \
    for (int i = 0; i < 4; i++)                                              \
        _Pragma("unroll")                                                    \
        for (int j = 0; j < 4; j++)                                          \
            acc[i][j] = MFMA_I8(af[i], bf[j], acc[i][j]);                    \
    __builtin_amdgcn_s_setprio(0);

    // waitcnt imm: vmcnt[3:0]=bits0-3, vmcnt[5:4]=bits14-15, lgkm=bits8-11.
    // 0xF70 = vmcnt(0) lgkm-ignore.
    stageA(0, 0);
    stageB(0, 0);
    __builtin_amdgcn_s_waitcnt(0xF70);
    __builtin_amdgcn_s_barrier();
    __builtin_amdgcn_sched_barrier(0);

#pragma unroll 1
    for (int t = 0; t < 32; ++t) {
        const signed char* Ac = As + (t & 1) * 32768;   // ring: tile t
        const signed char* Bc = Bs + (t & 1) * 32768;
        const int ktn = (t + 1) * 128;
        const int rn = (t + 1) & 1;

        // ---- q0 (s0,ks0): read frags; stage A(t+1); MFMA ----
        READ_FRAGS(Ac, Bc, 0, 0)
        if (t < 31) stageA(rn, ktn);
        __builtin_amdgcn_sched_barrier(0);
        QUARTER_MFMA
        __builtin_amdgcn_sched_barrier(0);

        // ---- q1 (s0,ks1): read frags; stage B(t+1); MFMA ----
        READ_FRAGS(Ac, Bc, 0, 1)
        if (t < 31) stageB(rn, ktn);
        __builtin_amdgcn_sched_barrier(0);
        QUARTER_MFMA
        __builtin_amdgcn_sched_barrier(0);

        // ---- q2 (s1,ks0): read frags; MFMA ----
        READ_FRAGS(Ac, Bc, 16384, 0)
        __builtin_amdgcn_sched_barrier(0);
        QUARTER_MFMA
        __builtin_amdgcn_sched_barrier(0);

        // ---- q3 (s1,ks1): read frags; MFMA ----
        READ_FRAGS(Ac, Bc, 16384, 1)
        __builtin_amdgcn_sched_barrier(0);
        QUARTER_MFMA
        __builtin_amdgcn_sched_barrier(0);

        // ---- boundary: tile t+1 landed; publish cross-wave. All own reads
        //      of ring t&1 completed (they fed q0-q3 MFMAs) -> stage(t+2)
        //      may overwrite ring t&1 only after this barrier. ----
        __builtin_amdgcn_s_waitcnt(0xF70);   // vmcnt(0)
        __builtin_amdgcn_s_barrier();
        __builtin_amdgcn_sched_barrier(0);
    }
#undef READ_FRAGS
#undef QUARTER_MFMA

    // Epilogue. C/D: col = lane&31, row = (reg&3) + 8*(reg>>2) + 4*kh
#pragma unroll
    for (int i = 0; i < 4; i++) {
#pragma unroll
        for (int r = 0; r < 16; r++) {
            const int gm = bm + wm + i * 32 + (r & 3) + 8 * (r >> 2) + 4 * kh;
            const int rcorr = -32 * rs[gm] - 8650752;
#pragma unroll
            for (int j = 0; j < 4; j++) {
                const int gn = bn + wn + j * 32 + mr;
                const int v = acc[i][j][r] + rcorr + 66 * sy[gn];
                C[(size_t)gm * 4096 + gn] = 7.5e-4f * (float)v;
            }
        }
    }
}

// ---------------------------------------------------------------------------
extern "C" void kernel_launch(void* const* d_in, const int* in_sizes, int n_in,
                              void* d_out, int out_size, void* d_ws, size_t ws_size,
                              hipStream_t stream) {
    const float* x = (const float*)d_in[0];  // [4096,4096] int8-valued
    const float* y = (const float*)d_in[1];  // [4096,4096] uint8-valued
    float* out = (float*)d_out;

    char* ws = (char*)d_ws;
    signed char* A8  = (signed char*)ws;                         // 16 MiB
    signed char* B8T = (signed char*)(ws + (16u << 20));         // 16 MiB
    int* rs = (int*)(ws + (32u << 20));                          // 16 KiB
    int* sy = (int*)(ws + (32u << 20) + (16u << 10));            // 16 KiB

    hipMemsetAsync(sy, 0, 4096 * sizeof(int), stream);
    quant_xy<<<5120, 256, 0, stream>>>(x, y, A8, B8T, rs, sy);
    gemm_i8<<<256, 256, 0, stream>>>(A8, B8T, rs, sy, out);
}

// Round 14
// 238.361 us; speedup vs baseline: 1.1329x; 1.0313x over previous
//
#include <hip/hip_runtime.h>
#include <cstdint>
#include <cstddef>

typedef int int32x4  __attribute__((ext_vector_type(4)));
typedef int int32x16 __attribute__((ext_vector_type(16)));

#define AS1 __attribute__((address_space(1)))
#define AS3 __attribute__((address_space(3)))

__device__ __forceinline__ void gload_lds16(const void* g, void* l) {
    __builtin_amdgcn_global_load_lds((const AS1 void*)g, (AS3 void*)l, 16, 0, 0);
}

#define MFMA_I8(a, b, c) __builtin_amdgcn_mfma_i32_32x32x32_i8((a), (b), (c), 0, 0, 0)

// ---------------------------------------------------------------------------
// Fused quant kernel (frozen r6 version).
// Blocks [0,4096): x-rows. Blocks [4096,5120): y 256n x 64k coalesced tiles.
// ---------------------------------------------------------------------------
__global__ __launch_bounds__(256) void quant_xy(const float* __restrict__ x,
                                                const float* __restrict__ y,
                                                signed char* __restrict__ A8,
                                                signed char* __restrict__ B8T,
                                                int* __restrict__ rs,
                                                int* __restrict__ sy) {
    const int t = threadIdx.x;
    if (blockIdx.x < 4096) {
        const int row = blockIdx.x;
        const float4* xr = (const float4*)(x + (size_t)row * 4096);
        char4* ar = (char4*)(A8 + (size_t)row * 4096);
        int s = 0;
#pragma unroll
        for (int i = 0; i < 4; i++) {
            const int idx = i * 256 + t;
            float4 v = xr[idx];
            int a0 = (int)v.x, a1 = (int)v.y, a2 = (int)v.z, a3 = (int)v.w;
            s += a0 + a1 + a2 + a3;
            char4 c;
            c.x = (signed char)a0; c.y = (signed char)a1;
            c.z = (signed char)a2; c.w = (signed char)a3;
            ar[idx] = c;
        }
#pragma unroll
        for (int off = 32; off > 0; off >>= 1) s += __shfl_down(s, off);
        __shared__ int wsum[4];
        if ((t & 63) == 0) wsum[t >> 6] = s;
        __syncthreads();
        if (t == 0) rs[row] = wsum[0] + wsum[1] + wsum[2] + wsum[3];
    } else {
        const int q = blockIdx.x - 4096;
        const int nt = (q & 15) * 256;
        const int kt = (q >> 4) * 64;
        __shared__ int tile_s[256 * 16];
        __shared__ int ssum[256];
        if (t < 256) ssum[t] = 0;
        __syncthreads();

        const int n4 = (t & 63) * 4;
        const int kg = (t >> 6) * 4;
        const int swzkey = t & 15;
        int s0 = 0, s1 = 0, s2 = 0, s3 = 0;
#pragma unroll
        for (int o = 0; o < 4; o++) {
            int b[4][4];
#pragma unroll
            for (int i = 0; i < 4; i++) {
                const int k = o * 16 + kg + i;
                float4 v = *(const float4*)(y + (size_t)(kt + k) * 4096 + nt + n4);
                b[i][0] = (int)v.x - 128; b[i][1] = (int)v.y - 128;
                b[i][2] = (int)v.z - 128; b[i][3] = (int)v.w - 128;
            }
            const int kd = o * 4 + (t >> 6);
            const int sw = kd ^ swzkey;
#pragma unroll
            for (int j = 0; j < 4; j++) {
                const int w = (b[0][j] & 255) | ((b[1][j] & 255) << 8) |
                              ((b[2][j] & 255) << 16) | (b[3][j] << 24);
                tile_s[(n4 + j) * 16 + sw] = w;
            }
            s0 += b[0][0] + b[1][0] + b[2][0] + b[3][0];
            s1 += b[0][1] + b[1][1] + b[2][1] + b[3][1];
            s2 += b[0][2] + b[1][2] + b[2][2] + b[3][2];
            s3 += b[0][3] + b[1][3] + b[2][3] + b[3][3];
        }
        atomicAdd(&ssum[n4 + 0], s0);
        atomicAdd(&ssum[n4 + 1], s1);
        atomicAdd(&ssum[n4 + 2], s2);
        atomicAdd(&ssum[n4 + 3], s3);
        __syncthreads();

        const int c = t & 3;
#pragma unroll
        for (int p = 0; p < 4; p++) {
            const int n = (t >> 2) + p * 64;
            const int key = (n >> 2) & 15;
            int32x4 o;
            o.x = tile_s[n * 16 + ((c * 4 + 0) ^ key)];
            o.y = tile_s[n * 16 + ((c * 4 + 1) ^ key)];
            o.z = tile_s[n * 16 + ((c * 4 + 2) ^ key)];
            o.w = tile_s[n * 16 + ((c * 4 + 3) ^ key)];
            *(int32x4*)(B8T + (size_t)(nt + n) * 4096 + kt + c * 16) = o;
        }
        if (t < 256) atomicAdd(&sy[nt + t], ssum[t]);
    }
}

// ---------------------------------------------------------------------------
// Kernel 3: int8 GEMM — r10 RESTORED (measured best: 74.7us gemm, 235.4us
// total) + epilogue sy-hoist (2 distinct gn per thread; was 128 reloads).
// Final ledger: schedules null (r0/r1/r3); small-tile ✗ (r2); reg-pipeline
// +12% (r4); A-from-global ✗ (r7); block-TLP null (r9); BK=128 +9% (r10);
// 4 waves/SIMD null (r11); 128x128 reg-tile ✗ spill (r12/r13). r10 is the
// local optimum: every unilateral departure regressed or nulled.
// Geometry: 256 blocks, 512 thr, tile 256x256, 8 waves 2Mx4N, wave tile
// 128x64; per tile 4 K-quarters (sub s x ks) of 8 MFMAs. BK=128, 2-ring
// LDS 128KB. Register frag pipeline: X frags feed even quarters, Y odd;
// each quarter's MFMAs run while the next quarter's frags are ds_read.
// Per-tile sync: q0 issues stage(t+1) [8 gloads]; ONE
// vmcnt(0)+lgkmcnt(0)+barrier boundary at q2/q3 (loads issued ~1750cy
// earlier, L2/L3-resident -> near-free drain); q3 prefetches tile t+1.
// Staging (m104/m108): dst = ring + s*16384 + p*8192 + tid*16; source row
// p*128+(tid>>2), chunk (tid&3)^((tid>>3)&3).
// Frags: A[m=lane&31][k=(lane>>5)*16+j]; C/D col=lane&31,
// row=(reg&3)+8*(reg>>2)+4*(lane>>5)  (verified r0-r13, absmax 32).
// Epilogue: C = 7.5e-4 * (P - 32*rs[m] + 66*sy[n] - 8650752)
// ---------------------------------------------------------------------------
__global__ __launch_bounds__(512, 2) void gemm_i8(const signed char* __restrict__ A8,
                                                  const signed char* __restrict__ B8T,
                                                  const int* __restrict__ rs,
                                                  const int* __restrict__ sy,
                                                  float* __restrict__ C) {
    __shared__ __align__(16) signed char As[2 * 32768];  // ring x (2 sub x 16KB)
    __shared__ __align__(16) signed char Bs[2 * 32768];
    const int tid = threadIdx.x;
    const int lin = blockIdx.x;
    const int til = (lin & 7) * 32 + (lin >> 3);   // XCD-contiguous tiles
    const int bm = (til >> 4) * 256;
    const int bn = (til & 15) * 256;
    const int lane = tid & 63;
    const int wave = tid >> 6;
    const int wm = (wave >> 2) * 128;   // 2 m-waves x 128
    const int wn = (wave & 3) * 64;     // 4 n-waves x 64
    const int mr = lane & 31;
    const int kh = lane >> 5;

    int32x16 acc[4][2] = {};

    // staging: thread -> row tid>>2 (+128p), source chunk (tid&3)^((tid>>3)&3);
    // dst = uniform base + tid*16 (+p*8192): matches global_load_lds layout.
    const size_t srowoff = (size_t)(tid >> 2) * 4096 +
                           (((tid & 3) ^ ((tid >> 3) & 3)) * 16);
    const size_t arow = (size_t)bm * 4096 + srowoff;
    const size_t brow = (size_t)bn * 4096 + srowoff;

    // fragment LDS offsets within a 16KB subtile: row*64 + slot*16,
    // slot = (ks*2+kh) ^ ((mr>>1)&3)
    int aoff[4][2], boff[2][2];
#pragma unroll
    for (int ks = 0; ks < 2; ks++) {
        const int slot = ((ks * 2 + kh) ^ ((mr >> 1) & 3)) * 16;
#pragma unroll
        for (int i = 0; i < 4; i++) aoff[i][ks] = (wm + i * 32 + mr) * 64 + slot;
#pragma unroll
        for (int j = 0; j < 2; j++) boff[j][ks] = (wn + j * 32 + mr) * 64 + slot;
    }

    auto stage = [&](int r, int kt) {   // 8 gloads: (2 sub x 2 p) x (A,B)
#pragma unroll
        for (int s = 0; s < 2; s++) {
            signed char* a_dst = As + r * 32768 + s * 16384 + tid * 16;
            signed char* b_dst = Bs + r * 32768 + s * 16384 + tid * 16;
#pragma unroll
            for (int p = 0; p < 2; p++) {
                gload_lds16(A8 + arow + (size_t)p * 524288 + kt + s * 64,
                            a_dst + p * 8192);
                gload_lds16(B8T + brow + (size_t)p * 524288 + kt + s * 64,
                            b_dst + p * 8192);
            }
        }
    };

    // waitcnt imm: vmcnt[3:0]=bits0-3, vmcnt[5:4]=bits14-15, exp=0x70 (ignore),
    // lgkm=bits8-11. 0xF70 = vmcnt(0), lgkm ignore. 0x070 = vmcnt(0)+lgkmcnt(0).
    stage(0, 0);
    __builtin_amdgcn_s_waitcnt(0xF70);
    __builtin_amdgcn_s_barrier();
    __builtin_amdgcn_sched_barrier(0);

    int32x4 xa[4], xb[2];   // frags for even quarters (q0, q2)
    int32x4 ya[4], yb[2];   // frags for odd quarters (q1, q3)
#pragma unroll
    for (int i = 0; i < 4; i++) xa[i] = *(const int32x4*)(As + aoff[i][0]);
#pragma unroll
    for (int j = 0; j < 2; j++) xb[j] = *(const int32x4*)(Bs + boff[j][0]);

#pragma unroll 1
    for (int t = 0; t < 32; ++t) {
        const signed char* Ac = As + (t & 1) * 32768;        // ring: tile t
        const signed char* Bc = Bs + (t & 1) * 32768;
        const signed char* An = As + ((t + 1) & 1) * 32768;  // ring: tile t+1
        const signed char* Bn = Bs + ((t + 1) & 1) * 32768;

        // ---- q0: read Y <- (t, s0, ks1); issue stage(t+1); MFMA X ----
#pragma unroll
        for (int i = 0; i < 4; i++) ya[i] = *(const int32x4*)(Ac + aoff[i][1]);
#pragma unroll
        for (int j = 0; j < 2; j++) yb[j] = *(const int32x4*)(Bc + boff[j][1]);
        if (t < 31) stage((t + 1) & 1, (t + 1) * 128);
        __builtin_amdgcn_sched_barrier(0);
        __builtin_amdgcn_s_setprio(1);
        acc[0][0] = MFMA_I8(xa[0], xb[0], acc[0][0]);
        acc[0][1] = MFMA_I8(xa[0], xb[1], acc[0][1]);
        acc[1][0] = MFMA_I8(xa[1], xb[0], acc[1][0]);
        acc[1][1] = MFMA_I8(xa[1], xb[1], acc[1][1]);
        acc[2][0] = MFMA_I8(xa[2], xb[0], acc[2][0]);
        acc[2][1] = MFMA_I8(xa[2], xb[1], acc[2][1]);
        acc[3][0] = MFMA_I8(xa[3], xb[0], acc[3][0]);
        acc[3][1] = MFMA_I8(xa[3], xb[1], acc[3][1]);
        __builtin_amdgcn_s_setprio(0);
        __builtin_amdgcn_sched_barrier(0);

        // ---- q1: read X <- (t, s1, ks0); MFMA Y ----
#pragma unroll
        for (int i = 0; i < 4; i++) xa[i] = *(const int32x4*)(Ac + 16384 + aoff[i][0]);
#pragma unroll
        for (int j = 0; j < 2; j++) xb[j] = *(const int32x4*)(Bc + 16384 + boff[j][0]);
        __builtin_amdgcn_sched_barrier(0);
        __builtin_amdgcn_s_setprio(1);
        acc[0][0] = MFMA_I8(ya[0], yb[0], acc[0][0]);
        acc[0][1] = MFMA_I8(ya[0], yb[1], acc[0][1]);
        acc[1][0] = MFMA_I8(ya[1], yb[0], acc[1][0]);
        acc[1][1] = MFMA_I8(ya[1], yb[1], acc[1][1]);
        acc[2][0] = MFMA_I8(ya[2], yb[0], acc[2][0]);
        acc[2][1] = MFMA_I8(ya[2], yb[1], acc[2][1]);
        acc[3][0] = MFMA_I8(ya[3], yb[0], acc[3][0]);
        acc[3][1] = MFMA_I8(ya[3], yb[1], acc[3][1]);
        __builtin_amdgcn_s_setprio(0);
        __builtin_amdgcn_sched_barrier(0);

        // ---- q2: read Y <- (t, s1, ks1); MFMA X ----
#pragma unroll
        for (int i = 0; i < 4; i++) ya[i] = *(const int32x4*)(Ac + 16384 + aoff[i][1]);
#pragma unroll
        for (int j = 0; j < 2; j++) yb[j] = *(const int32x4*)(Bc + 16384 + boff[j][1]);
        __builtin_amdgcn_sched_barrier(0);
        __builtin_amdgcn_s_setprio(1);
        acc[0][0] = MFMA_I8(xa[0], xb[0], acc[0][0]);
        acc[0][1] = MFMA_I8(xa[0], xb[1], acc[0][1]);
        acc[1][0] = MFMA_I8(xa[1], xb[0], acc[1][0]);
        acc[1][1] = MFMA_I8(xa[1], xb[1], acc[1][1]);
        acc[2][0] = MFMA_I8(xa[2], xb[0], acc[2][0]);
        acc[2][1] = MFMA_I8(xa[2], xb[1], acc[2][1]);
        acc[3][0] = MFMA_I8(xa[3], xb[0], acc[3][0]);
        acc[3][1] = MFMA_I8(xa[3], xb[1], acc[3][1]);
        __builtin_amdgcn_s_setprio(0);
        __builtin_amdgcn_sched_barrier(0);

        // ---- boundary: tile t+1 landed (own) + all reads of ring (t+1)&1
        //      drained (lgkm 0) -> barrier publishes both cross-wave ----
        __builtin_amdgcn_s_waitcnt(0x070);   // vmcnt(0) + lgkmcnt(0)
        __builtin_amdgcn_s_barrier();
        __builtin_amdgcn_sched_barrier(0);

        // ---- q3: read X <- (t+1, s0, ks0); MFMA Y ----
        if (t < 31) {
#pragma unroll
            for (int i = 0; i < 4; i++) xa[i] = *(const int32x4*)(An + aoff[i][0]);
#pragma unroll
            for (int j = 0; j < 2; j++) xb[j] = *(const int32x4*)(Bn + boff[j][0]);
        }
        __builtin_amdgcn_sched_barrier(0);
        __builtin_amdgcn_s_setprio(1);
        acc[0][0] = MFMA_I8(ya[0], yb[0], acc[0][0]);
        acc[0][1] = MFMA_I8(ya[0], yb[1], acc[0][1]);
        acc[1][0] = MFMA_I8(ya[1], yb[0], acc[1][0]);
        acc[1][1] = MFMA_I8(ya[1], yb[1], acc[1][1]);
        acc[2][0] = MFMA_I8(ya[2], yb[0], acc[2][0]);
        acc[2][1] = MFMA_I8(ya[2], yb[1], acc[2][1]);
        acc[3][0] = MFMA_I8(ya[3], yb[0], acc[3][0]);
        acc[3][1] = MFMA_I8(ya[3], yb[1], acc[3][1]);
        __builtin_amdgcn_s_setprio(0);
    }

    // Epilogue. C/D: col = lane&31, row = (reg&3) + 8*(reg>>2) + 4*kh.
    // sy-hoist: each thread touches only 2 distinct columns (j=0,1).
    const int gn0 = bn + wn + mr;
    const int syt0 = 66 * sy[gn0] - 8650752;
    const int syt1 = 66 * sy[gn0 + 32] - 8650752;
    float* C0 = C + gn0;
#pragma unroll
    for (int i = 0; i < 4; i++) {
#pragma unroll
        for (int r = 0; r < 16; r++) {
            const int gm = bm + wm + i * 32 + (r & 3) + 8 * (r >> 2) + 4 * kh;
            const int rcorr = -32 * rs[gm];
            float* Crow = C0 + (size_t)gm * 4096;
            Crow[0]  = 7.5e-4f * (float)(acc[i][0][r] + rcorr + syt0);
            Crow[32] = 7.5e-4f * (float)(acc[i][1][r] + rcorr + syt1);
        }
    }
}

// ---------------------------------------------------------------------------
extern "C" void kernel_launch(void* const* d_in, const int* in_sizes, int n_in,
                              void* d_out, int out_size, void* d_ws, size_t ws_size,
                              hipStream_t stream) {
    const float* x = (const float*)d_in[0];  // [4096,4096] int8-valued
    const float* y = (const float*)d_in[1];  // [4096,4096] uint8-valued
    float* out = (float*)d_out;

    char* ws = (char*)d_ws;
    signed char* A8  = (signed char*)ws;                         // 16 MiB
    signed char* B8T = (signed char*)(ws + (16u << 20));         // 16 MiB
    int* rs = (int*)(ws + (32u << 20));                          // 16 KiB
    int* sy = (int*)(ws + (32u << 20) + (16u << 10));            // 16 KiB

    hipMemsetAsync(sy, 0, 4096 * sizeof(int), stream);
    quant_xy<<<5120, 256, 0, stream>>>(x, y, A8, B8T, rs, sy);
    gemm_i8<<<256, 512, 0, stream>>>(A8, B8T, rs, sy, out);
}